// Round 2
// baseline (1062.146 us; speedup 1.0000x reference)
//
#include <hip/hip_runtime.h>
#include <hip/hip_cooperative_groups.h>
#include <stdint.h>

namespace cg = cooperative_groups;

#define D_DIM 128
#define EPS_LN 1e-6f
#define NA 20480   // padded node-array stride (N=20000 fits, +1 ok)

// robust fast tanh: exact at +/-inf, ~1e-6 rel err
__device__ __forceinline__ float tanh_fast(float x) {
    return 1.0f - 2.0f / (__expf(2.0f * x) + 1.0f);
}

__device__ __forceinline__ float wave_sum(float v) {
    #pragma unroll
    for (int m = 1; m < 64; m <<= 1) v += __shfl_xor(v, m, 64);
    return v;
}

// reduce across a 16-lane group (xor masks 1,2,4,8 stay inside the group)
__device__ __forceinline__ float group16_sum(float v) {
    #pragma unroll
    for (int m = 1; m < 16; m <<= 1) v += __shfl_xor(v, m, 64);
    return v;
}

__device__ __forceinline__ float dot8_ln(const float4& a, const float4& b,
                                         float mean, float inv,
                                         const float4& wa0, const float4& wa1,
                                         const float4& wb0, const float4& wb1,
                                         const float4& ww0, const float4& ww1) {
    float p = 0.0f;
    p += ((a.x - mean) * inv * wa0.x + wb0.x) * ww0.x;
    p += ((a.y - mean) * inv * wa0.y + wb0.y) * ww0.y;
    p += ((a.z - mean) * inv * wa0.z + wb0.z) * ww0.z;
    p += ((a.w - mean) * inv * wa0.w + wb0.w) * ww0.w;
    p += ((b.x - mean) * inv * wa1.x + wb1.x) * ww1.x;
    p += ((b.y - mean) * inv * wa1.y + wb1.y) * ww1.y;
    p += ((b.z - mean) * inv * wa1.z + wb1.z) * ww1.z;
    p += ((b.w - mean) * inv * wa1.w + wb1.w) * ww1.w;
    return p;
}

// Single cooperative kernel; phases separated by grid.sync().
// P0: zero cnt + node logits (eh, et)
// P1: edge logits -> ex; rank = atomicAdd(cnt+dst) gives within-node slot
// P2: per-block chunk scans of cnt (chunk-local exclusive) + block sums
// P3: block 0 scans block sums -> bpre
// P4: scatter (src, ex) into CSR slot off(d)+rank  [no atomics]
// P5: per-node gather + GEMV + L2-normalize
__global__ __launch_bounds__(256) void k_fused(
    const float* __restrict__ h, const float* __restrict__ r,
    const int* __restrict__ src, const int* __restrict__ dst,
    const float* __restrict__ hn_a, const float* __restrict__ hn_b,
    const float* __restrict__ tn_a, const float* __restrict__ tn_b,
    const float* __restrict__ rn_a, const float* __restrict__ rn_b,
    const float* __restrict__ head_w, const float* __restrict__ tail_w,
    const float* __restrict__ rel_w,
    const float* __restrict__ fc_w, const float* __restrict__ fc_b,
    float* __restrict__ out, float* __restrict__ ws,
    int n, int nE)
{
    cg::grid_group gg = cg::this_grid();

    float* eh   = ws;
    float* et   = ws + NA;
    int*   cnt  = (int*)(ws + 2 * NA);
    int*   offl = (int*)(ws + 3 * NA);            // chunk-local exclusive scan
    int*   bsum = (int*)(ws + 4 * NA);            // [256] per-chunk totals
    int*   bpre = bsum + 256;                     // [256] exclusive prefix of bsum
    int2*  emeta = (int2*)(ws + 4 * NA + 512);    // [E] {rank, ex bits}
    int2*  edata = emeta + nE;                    // [E] {src, ex bits} CSR-ordered

    const int gthreads = gridDim.x * 256;
    const int gtid = blockIdx.x * 256 + threadIdx.x;
    const int sub  = threadIdx.x & 15;

    __shared__ float feat[4][128];
    __shared__ int sscan[4];

    // ---------------- P0: zero histogram + per-node logits ----------------
    for (int i = gtid; i < NA; i += gthreads) cnt[i] = 0;

    for (int unit = gtid; unit < n * 16; unit += gthreads) {
        int node = unit >> 4;
        const float4* hp = (const float4*)(h + (size_t)node * 128);
        float4 a = hp[sub * 2], b = hp[sub * 2 + 1];

        float s  = a.x + a.y + a.z + a.w + b.x + b.y + b.z + b.w;
        float s2 = a.x*a.x + a.y*a.y + a.z*a.z + a.w*a.w
                 + b.x*b.x + b.y*b.y + b.z*b.z + b.w*b.w;
        s  = group16_sum(s);
        s2 = group16_sum(s2);
        float mean = s * (1.0f / 128.0f);
        float var  = fmaxf((s2 - s * mean) * (1.0f / 127.0f), 0.0f);
        float inv  = 1.0f / (sqrtf(var) + EPS_LN);

        int i0 = sub * 2, i1 = sub * 2 + 1;
        float4 ha0 = ((const float4*)hn_a)[i0],  ha1 = ((const float4*)hn_a)[i1];
        float4 hb0 = ((const float4*)hn_b)[i0],  hb1 = ((const float4*)hn_b)[i1];
        float4 hw0 = ((const float4*)head_w)[i0],hw1 = ((const float4*)head_w)[i1];
        float4 ta0 = ((const float4*)tn_a)[i0],  ta1 = ((const float4*)tn_a)[i1];
        float4 tb0 = ((const float4*)tn_b)[i0],  tb1 = ((const float4*)tn_b)[i1];
        float4 tw0 = ((const float4*)tail_w)[i0],tw1 = ((const float4*)tail_w)[i1];

        float ph = dot8_ln(a, b, mean, inv, ha0, ha1, hb0, hb1, hw0, hw1);
        float pt = dot8_ln(a, b, mean, inv, ta0, ta1, tb0, tb1, tw0, tw1);
        ph = group16_sum(ph);
        pt = group16_sum(pt);
        if (sub == 0) {
            eh[node] = tanh_fast(ph);
            et[node] = tanh_fast(pt);
        }
    }
    gg.sync();   // S1

    // ---------------- P1: per-edge logits + rank assignment ----------------
    for (int unit = gtid; unit < nE * 16; unit += gthreads) {
        int edge = unit >> 4;
        int sN = 0, dN = 0;
        float vh = 0.0f, vt = 0.0f;
        if (sub == 0) {           // prefetch early; overlaps LN compute
            sN = src[edge]; dN = dst[edge];
            vh = eh[sN];    vt = et[dN];
        }
        const float4* rp = (const float4*)(r + (size_t)edge * 128);
        float4 a = rp[sub * 2], b = rp[sub * 2 + 1];

        float s  = a.x + a.y + a.z + a.w + b.x + b.y + b.z + b.w;
        float s2 = a.x*a.x + a.y*a.y + a.z*a.z + a.w*a.w
                 + b.x*b.x + b.y*b.y + b.z*b.z + b.w*b.w;
        s  = group16_sum(s);
        s2 = group16_sum(s2);
        float mean = s * (1.0f / 128.0f);
        float var  = fmaxf((s2 - s * mean) * (1.0f / 127.0f), 0.0f);
        float inv  = 1.0f / (sqrtf(var) + EPS_LN);

        int i0 = sub * 2, i1 = sub * 2 + 1;
        float4 ra0 = ((const float4*)rn_a)[i0],  ra1 = ((const float4*)rn_a)[i1];
        float4 rb0 = ((const float4*)rn_b)[i0],  rb1 = ((const float4*)rn_b)[i1];
        float4 rw0 = ((const float4*)rel_w)[i0], rw1 = ((const float4*)rel_w)[i1];

        float pr = dot8_ln(a, b, mean, inv, ra0, ra1, rb0, rb1, rw0, rw1);
        pr = group16_sum(pr);

        if (sub == 0) {
            float v = tanh_fast(pr) + vh + vt;
            v = fmaxf(v, 0.0f);                     // e in [0,3): exp safe, max-shift not needed
            int rank = atomicAdd(cnt + dN, 1);      // histogram + within-node slot
            emeta[edge] = make_int2(rank, __float_as_int(__expf(v)));
        }
    }
    gg.sync();   // S2

    // ---------------- P2: chunk-local exclusive scans ----------------
    const int B1 = (n + 256) >> 8;     // chunks covering indices 0..n
    for (int b = blockIdx.x; b < B1; b += gridDim.x) {
        int i = (b << 8) + threadIdx.x;
        int v = (i < n) ? cnt[i] : 0;
        int lane = threadIdx.x & 63, w4 = threadIdx.x >> 6;
        int x = v;
        #pragma unroll
        for (int s = 1; s < 64; s <<= 1) {
            int t = __shfl_up(x, s, 64);
            if (lane >= s) x += t;
        }
        if (lane == 63) sscan[w4] = x;
        __syncthreads();
        if (threadIdx.x == 0) {
            int a0 = sscan[0], a1 = sscan[1], a2 = sscan[2], a3 = sscan[3];
            sscan[0] = 0; sscan[1] = a0; sscan[2] = a0 + a1; sscan[3] = a0 + a1 + a2;
            bsum[b] = a0 + a1 + a2 + a3;
        }
        __syncthreads();
        offl[i] = sscan[w4] + x - v;   // chunk-local exclusive
        __syncthreads();
    }
    gg.sync();   // S3

    // ---------------- P3: scan of chunk totals (block 0 only) ----------------
    if (blockIdx.x == 0) {
        int t = threadIdx.x;
        int v = (t < B1) ? bsum[t] : 0;
        int lane = t & 63, w4 = t >> 6;
        int x = v;
        #pragma unroll
        for (int s = 1; s < 64; s <<= 1) {
            int tt = __shfl_up(x, s, 64);
            if (lane >= s) x += tt;
        }
        if (lane == 63) sscan[w4] = x;
        __syncthreads();
        if (t == 0) {
            int a0 = sscan[0], a1 = sscan[1], a2 = sscan[2], a3 = sscan[3];
            sscan[0] = 0; sscan[1] = a0; sscan[2] = a0 + a1; sscan[3] = a0 + a1 + a2;
        }
        __syncthreads();
        bpre[t] = sscan[w4] + x - v;   // exclusive prefix of chunk totals
    }
    gg.sync();   // S4

    // ---------------- P4: atomic-free scatter into CSR ----------------
    for (int e = gtid; e < nE; e += gthreads) {
        int d = dst[e];
        int2 m = emeta[e];
        int slot = offl[d] + bpre[d >> 8] + m.x;
        edata[slot] = make_int2(src[e], m.y);      // one packed 8B store
    }
    gg.sync();   // S5

    // ---------------- P5: gather + GEMV + normalize ----------------
    {
        int gw = gtid >> 6, lane = gtid & 63, wid = threadIdx.x >> 6;
        int nwaves = gthreads >> 6;
        const float2* h2 = (const float2*)h;
        const float2* w2 = (const float2*)fc_w;
        float2 bb = ((const float2*)fc_b)[lane];

        for (int v = gw; v < n; v += nwaves) {
            int beg = offl[v]     + bpre[v >> 8];
            int end = offl[v + 1] + bpre[(v + 1) >> 8];

            float acc0 = 0.0f, acc1 = 0.0f;   // even slots
            float acc2 = 0.0f, acc3 = 0.0f;   // odd slots
            float ws0 = 0.0f, ws1 = 0.0f;

            for (int i = beg; i < end; i += 8) {
                int m = end - i;               // wave-uniform
                int2   q_[8];
                float2 p_[8];
                #pragma unroll
                for (int j = 0; j < 8; j++)
                    if (j < m) q_[j] = edata[i + j];
                #pragma unroll
                for (int j = 0; j < 8; j++)
                    if (j < m) p_[j] = h2[(size_t)q_[j].x * 64 + lane];
                #pragma unroll
                for (int j = 0; j < 8; j += 2) {
                    if (j < m) {
                        float w = __int_as_float(q_[j].y);
                        acc0 += w * p_[j].x; acc1 += w * p_[j].y; ws0 += w;
                    }
                    if (j + 1 < m) {
                        float w = __int_as_float(q_[j + 1].y);
                        acc2 += w * p_[j + 1].x; acc3 += w * p_[j + 1].y; ws1 += w;
                    }
                }
            }
            acc0 += acc2; acc1 += acc3;
            float wsum = ws0 + ws1;

            float inv = (end > beg) ? (1.0f / wsum) : 0.0f;
            feat[wid][lane * 2]     = acc0 * inv;
            feat[wid][lane * 2 + 1] = acc1 * inv;
            // same-wave LDS write->read: DS ops execute in wave order

            float o0 = bb.x, o1 = bb.y;
            #pragma unroll 8
            for (int d = 0; d < 128; d++) {
                float f = feat[wid][d];
                float2 ww = w2[d * 64 + lane];
                o0 += f * ww.x;
                o1 += f * ww.y;
            }

            float nrm2 = wave_sum(o0 * o0 + o1 * o1);
            float invn = 1.0f / fmaxf(sqrtf(nrm2), 1e-12f);
            float2 q; q.x = o0 * invn; q.y = o1 * invn;
            ((float2*)out)[(size_t)v * 64 + lane] = q;
        }
    }
}

extern "C" void kernel_launch(void* const* d_in, const int* in_sizes, int n_in,
                              void* d_out, int out_size, void* d_ws, size_t ws_size,
                              hipStream_t stream)
{
    const float* h      = (const float*)d_in[0];
    const float* r      = (const float*)d_in[1];
    const int*   src    = (const int*)d_in[2];
    const int*   dst    = (const int*)d_in[3];
    const float* hn_a   = (const float*)d_in[4];
    const float* hn_b   = (const float*)d_in[5];
    const float* tn_a   = (const float*)d_in[6];
    const float* tn_b   = (const float*)d_in[7];
    const float* rn_a   = (const float*)d_in[8];
    const float* rn_b   = (const float*)d_in[9];
    const float* head_w = (const float*)d_in[10];
    const float* tail_w = (const float*)d_in[11];
    const float* rel_w  = (const float*)d_in[12];
    const float* fc_w   = (const float*)d_in[13];
    const float* fc_b   = (const float*)d_in[14];

    int N = in_sizes[0] / D_DIM;
    int E = in_sizes[2];

    float* outp = (float*)d_out;
    float* wsp  = (float*)d_ws;

    // co-resident grid size: query once, cache (host-only API, capture-safe)
    static int gblocks = 0;
    if (gblocks == 0) {
        int occ = 0;
        hipOccupancyMaxActiveBlocksPerMultiprocessor(&occ, k_fused, 256, 0);
        if (occ < 1) occ = 1;
        hipDeviceProp_t prop;
        hipGetDeviceProperties(&prop, 0);
        gblocks = occ * prop.multiProcessorCount;
        if (gblocks > 2048) gblocks = 2048;
        if (gblocks < 128)  gblocks = 128;   // must cover B1=79 scan chunks
    }

    void* args[] = {
        (void*)&h, (void*)&r, (void*)&src, (void*)&dst,
        (void*)&hn_a, (void*)&hn_b, (void*)&tn_a, (void*)&tn_b,
        (void*)&rn_a, (void*)&rn_b,
        (void*)&head_w, (void*)&tail_w, (void*)&rel_w,
        (void*)&fc_w, (void*)&fc_b,
        (void*)&outp, (void*)&wsp, (void*)&N, (void*)&E };

    hipLaunchCooperativeKernel((const void*)k_fused, dim3(gblocks), dim3(256),
                               args, 0, stream);
}

// Round 4
// 590.623 us; speedup vs baseline: 1.7983x; 1.7983x over previous
//
#include <hip/hip_runtime.h>
#include <stdint.h>

#define D_DIM 128
#define EPS_LN 1e-6f
#define NA 20480   // padded node-array stride (N=20000 fits, N+1 ok)

// robust fast tanh: exact at +/-inf, ~1e-6 rel err
__device__ __forceinline__ float tanh_fast(float x) {
    return 1.0f - 2.0f / (__expf(2.0f * x) + 1.0f);
}

__device__ __forceinline__ float wave_sum(float v) {
    #pragma unroll
    for (int m = 1; m < 64; m <<= 1) v += __shfl_xor(v, m, 64);
    return v;
}

// reduce across a 16-lane group (xor masks 1,2,4,8 stay inside the group)
__device__ __forceinline__ float group16_sum(float v) {
    #pragma unroll
    for (int m = 1; m < 16; m <<= 1) v += __shfl_xor(v, m, 64);
    return v;
}

__device__ __forceinline__ float dot8_ln(const float4& a, const float4& b,
                                         float mean, float inv,
                                         const float4& wa0, const float4& wa1,
                                         const float4& wb0, const float4& wb1,
                                         const float4& ww0, const float4& ww1) {
    float p = 0.0f;
    p += ((a.x - mean) * inv * wa0.x + wb0.x) * ww0.x;
    p += ((a.y - mean) * inv * wa0.y + wb0.y) * ww0.y;
    p += ((a.z - mean) * inv * wa0.z + wb0.z) * ww0.z;
    p += ((a.w - mean) * inv * wa0.w + wb0.w) * ww0.w;
    p += ((b.x - mean) * inv * wa1.x + wb1.x) * ww1.x;
    p += ((b.y - mean) * inv * wa1.y + wb1.y) * ww1.y;
    p += ((b.z - mean) * inv * wa1.z + wb1.z) * ww1.z;
    p += ((b.w - mean) * inv * wa1.w + wb1.w) * ww1.w;
    return p;
}

// ---------------- per-node logits: eh = tanh(LN(h;hn)·head_w), et = tanh(LN(h;tn)·tail_w)
__global__ __launch_bounds__(256) void k_node(
    const float* __restrict__ h,
    const float* __restrict__ hn_a, const float* __restrict__ hn_b,
    const float* __restrict__ tn_a, const float* __restrict__ tn_b,
    const float* __restrict__ head_w, const float* __restrict__ tail_w,
    float* __restrict__ eh, float* __restrict__ et, int n)
{
    int gid  = blockIdx.x * 256 + threadIdx.x;
    int node = gid >> 4;
    int sub  = threadIdx.x & 15;
    if (node >= n) return;

    const float4* hp = (const float4*)(h + (size_t)node * 128);
    float4 a = hp[sub * 2], b = hp[sub * 2 + 1];

    float s  = a.x + a.y + a.z + a.w + b.x + b.y + b.z + b.w;
    float s2 = a.x*a.x + a.y*a.y + a.z*a.z + a.w*a.w
             + b.x*b.x + b.y*b.y + b.z*b.z + b.w*b.w;
    s  = group16_sum(s);
    s2 = group16_sum(s2);
    float mean = s * (1.0f / 128.0f);
    float var  = fmaxf((s2 - s * mean) * (1.0f / 127.0f), 0.0f);
    float inv  = 1.0f / (sqrtf(var) + EPS_LN);

    int i0 = sub * 2, i1 = sub * 2 + 1;
    float4 ha0 = ((const float4*)hn_a)[i0],  ha1 = ((const float4*)hn_a)[i1];
    float4 hb0 = ((const float4*)hn_b)[i0],  hb1 = ((const float4*)hn_b)[i1];
    float4 hw0 = ((const float4*)head_w)[i0],hw1 = ((const float4*)head_w)[i1];
    float4 ta0 = ((const float4*)tn_a)[i0],  ta1 = ((const float4*)tn_a)[i1];
    float4 tb0 = ((const float4*)tn_b)[i0],  tb1 = ((const float4*)tn_b)[i1];
    float4 tw0 = ((const float4*)tail_w)[i0],tw1 = ((const float4*)tail_w)[i1];

    float ph = dot8_ln(a, b, mean, inv, ha0, ha1, hb0, hb1, hw0, hw1);
    float pt = dot8_ln(a, b, mean, inv, ta0, ta1, tb0, tb1, tw0, tw1);
    ph = group16_sum(ph);
    pt = group16_sum(pt);

    if (sub == 0) {
        eh[node] = tanh_fast(ph);
        et[node] = tanh_fast(pt);
    }
}

// ---------------- degree histogram (cheap pre-pass so k_edge can write CSR directly)
__global__ __launch_bounds__(256) void k_histo(
    const int* __restrict__ dst, int* __restrict__ cnt, int nE)
{
    int e = blockIdx.x * 256 + threadIdx.x;
    if (e < nE) atomicAdd(cnt + dst[e], 1);
}

// ---------------- parallel scan stage A: per-chunk (256-wide) exclusive scan + chunk totals
__global__ __launch_bounds__(256) void k_scanA(
    const int* __restrict__ cnt, int* __restrict__ offl,
    int* __restrict__ bsum, int n)
{
    __shared__ int sscan[4];
    int b = blockIdx.x;
    int i = (b << 8) + threadIdx.x;
    int v = (i < n) ? cnt[i] : 0;
    int lane = threadIdx.x & 63, w4 = threadIdx.x >> 6;
    int x = v;
    #pragma unroll
    for (int s = 1; s < 64; s <<= 1) {
        int t = __shfl_up(x, s, 64);
        if (lane >= s) x += t;
    }
    if (lane == 63) sscan[w4] = x;
    __syncthreads();
    if (threadIdx.x == 0) {
        int a0 = sscan[0], a1 = sscan[1], a2 = sscan[2], a3 = sscan[3];
        sscan[0] = 0; sscan[1] = a0; sscan[2] = a0 + a1; sscan[3] = a0 + a1 + a2;
        bsum[b] = a0 + a1 + a2 + a3;
    }
    __syncthreads();
    offl[i] = sscan[w4] + x - v;   // chunk-local exclusive
}

// ---------------- scan stage B: exclusive scan of chunk totals (1 block, nb<=256)
__global__ __launch_bounds__(256) void k_scanB(
    const int* __restrict__ bsum, int* __restrict__ bpre, int nb)
{
    __shared__ int sscan[4];
    int t = threadIdx.x;
    int v = (t < nb) ? bsum[t] : 0;
    int lane = t & 63, w4 = t >> 6;
    int x = v;
    #pragma unroll
    for (int s = 1; s < 64; s <<= 1) {
        int tt = __shfl_up(x, s, 64);
        if (lane >= s) x += tt;
    }
    if (lane == 63) sscan[w4] = x;
    __syncthreads();
    if (t == 0) {
        int a0 = sscan[0], a1 = sscan[1], a2 = sscan[2], a3 = sscan[3];
        sscan[0] = 0; sscan[1] = a0; sscan[2] = a0 + a1; sscan[3] = a0 + a1 + a2;
    }
    __syncthreads();
    bpre[t] = sscan[w4] + x - v;
}

// ---------------- scan stage C: combine into final CSR offsets off[0..n]
__global__ __launch_bounds__(256) void k_combine(
    const int* __restrict__ offl, const int* __restrict__ bpre,
    int* __restrict__ off, int n)
{
    int i = blockIdx.x * 256 + threadIdx.x;
    if (i <= n) off[i] = offl[i] + bpre[i >> 8];
}

// ---------------- per-edge: er = tanh(LN(r;rn)·rel_w); e = relu(eh[src]+et[dst]+er)
// Writes CSR slot DIRECTLY: slot = off[dst] + rank (rank via atomic). One packed
// 8B store {src, exp(e)}; no separate scatter pass. e in [0,3): exp safe un-shifted.
__global__ __launch_bounds__(256) void k_edge(
    const float* __restrict__ r,
    const float* __restrict__ rn_a, const float* __restrict__ rn_b,
    const float* __restrict__ rel_w,
    const int* __restrict__ src, const int* __restrict__ dst,
    const float* __restrict__ eh, const float* __restrict__ et,
    const int* __restrict__ off, int* __restrict__ rankc,
    int2* __restrict__ edata, int nE)
{
    int gid  = blockIdx.x * 256 + threadIdx.x;
    int edge = gid >> 4;
    int sub  = threadIdx.x & 15;
    if (edge >= nE) return;

    // early prefetch (writer lane only); latency overlaps LN compute below
    int sN = 0, dN = 0, base = 0;
    float vh = 0.0f, vt = 0.0f;
    if (sub == 0) {
        sN = src[edge]; dN = dst[edge];
        vh = eh[sN];    vt = et[dN];
        base = off[dN];
    }

    const float4* rp = (const float4*)(r + (size_t)edge * 128);
    float4 a = rp[sub * 2], b = rp[sub * 2 + 1];

    float s  = a.x + a.y + a.z + a.w + b.x + b.y + b.z + b.w;
    float s2 = a.x*a.x + a.y*a.y + a.z*a.z + a.w*a.w
             + b.x*b.x + b.y*b.y + b.z*b.z + b.w*b.w;
    s  = group16_sum(s);
    s2 = group16_sum(s2);
    float mean = s * (1.0f / 128.0f);
    float var  = fmaxf((s2 - s * mean) * (1.0f / 127.0f), 0.0f);
    float inv  = 1.0f / (sqrtf(var) + EPS_LN);

    int i0 = sub * 2, i1 = sub * 2 + 1;
    float4 ra0 = ((const float4*)rn_a)[i0],  ra1 = ((const float4*)rn_a)[i1];
    float4 rb0 = ((const float4*)rn_b)[i0],  rb1 = ((const float4*)rn_b)[i1];
    float4 rw0 = ((const float4*)rel_w)[i0], rw1 = ((const float4*)rel_w)[i1];

    float pr = dot8_ln(a, b, mean, inv, ra0, ra1, rb0, rb1, rw0, rw1);
    pr = group16_sum(pr);

    if (sub == 0) {
        float v = tanh_fast(pr) + vh + vt;
        v = fmaxf(v, 0.0f);
        int rank = atomicAdd(rankc + dN, 1);
        edata[base + rank] = make_int2(sN, __float_as_int(__expf(v)));
    }
}

// ---------------- per-node gather: feat[v] = (1/sum w) * sum w*h[src]
// One wave per node; 8-deep batched pipeline hides L2/LLC gather latency.
__global__ __launch_bounds__(256) void k_gather(
    const float* __restrict__ h,
    const int* __restrict__ off, const int2* __restrict__ edata,
    float* __restrict__ feat, int n)
{
    int wid = threadIdx.x >> 6, lane = threadIdx.x & 63;
    int v = blockIdx.x * 4 + wid;
    if (v >= n) return;

    int beg = off[v], end = off[v + 1];
    const float2* h2 = (const float2*)h;

    float acc0 = 0.0f, acc1 = 0.0f;   // even slots
    float acc2 = 0.0f, acc3 = 0.0f;   // odd slots (breaks FMA dep chain)
    float ws0 = 0.0f, ws1 = 0.0f;

    for (int i = beg; i < end; i += 8) {
        int m = end - i;               // wave-uniform
        int2   q_[8];
        float2 p_[8];
        #pragma unroll
        for (int j = 0; j < 8; j++)
            if (j < m) q_[j] = edata[i + j];
        #pragma unroll
        for (int j = 0; j < 8; j++)
            if (j < m) p_[j] = h2[(size_t)q_[j].x * 64 + lane];
        #pragma unroll
        for (int j = 0; j < 8; j += 2) {
            if (j < m) {
                float w = __int_as_float(q_[j].y);
                acc0 += w * p_[j].x; acc1 += w * p_[j].y; ws0 += w;
            }
            if (j + 1 < m) {
                float w = __int_as_float(q_[j + 1].y);
                acc2 += w * p_[j + 1].x; acc3 += w * p_[j + 1].y; ws1 += w;
            }
        }
    }
    acc0 += acc2; acc1 += acc3;
    float wsum = ws0 + ws1;

    float inv = (end > beg) ? (1.0f / wsum) : 0.0f;
    float2 q; q.x = acc0 * inv; q.y = acc1 * inv;
    ((float2*)feat)[(size_t)v * 64 + lane] = q;
}

// ---------------- GEMV + L2-normalize: out[v] = normalize(feat[v]@W + b)
// 16 nodes/block; fc_w staged in LDS in 32KB halves, shared by 4 waves
// (cuts fc_w L2 traffic 16x vs per-wave streaming). feat staged in LDS (8KB).
__global__ __launch_bounds__(256) void k_gemv(
    const float* __restrict__ feat,
    const float* __restrict__ fc_w, const float* __restrict__ fc_b,
    float* __restrict__ out, int n)
{
    __shared__ float wl[64][128];   // 32 KB: half of fc_w
    __shared__ float fl[16][128];   // 8 KB: this block's 16 feat rows
    int tid = threadIdx.x, lane = tid & 63, wid = tid >> 6;
    int vbase = blockIdx.x * 16;

    // stage feat rows (zero-pad past n)
    {
        const float4* fp = (const float4*)(feat + (size_t)vbase * 128);
        for (int k = tid; k < 512; k += 256) {       // 512 float4 = 16x128
            int row = k >> 5;
            ((float4*)fl)[k] = (vbase + row < n) ? fp[k] : make_float4(0, 0, 0, 0);
        }
    }

    float o0[4], o1[4];
    float2 bb = ((const float2*)fc_b)[lane];
    #pragma unroll
    for (int t = 0; t < 4; t++) { o0[t] = bb.x; o1[t] = bb.y; }

    for (int half = 0; half < 2; half++) {
        __syncthreads();   // feat staged (iter0) / previous compute done (iter1)
        const float4* wp = (const float4*)(fc_w + half * 64 * 128);
        for (int k = tid; k < 2048; k += 256)        // 2048 float4 = 64x128
            ((float4*)wl)[k] = wp[k];
        __syncthreads();
        #pragma unroll 4
        for (int d = 0; d < 64; d++) {
            float2 ww = ((const float2*)(wl[d]))[lane];   // contiguous, conflict-free
            #pragma unroll
            for (int t = 0; t < 4; t++) {
                float f = fl[wid * 4 + t][half * 64 + d]; // LDS broadcast
                o0[t] += f * ww.x;
                o1[t] += f * ww.y;
            }
        }
    }

    #pragma unroll
    for (int t = 0; t < 4; t++) {
        int v = vbase + wid * 4 + t;
        if (v >= n) continue;
        float nrm2 = wave_sum(o0[t] * o0[t] + o1[t] * o1[t]);
        float invn = 1.0f / fmaxf(sqrtf(nrm2), 1e-12f);
        float2 q; q.x = o0[t] * invn; q.y = o1[t] * invn;
        ((float2*)out)[(size_t)v * 64 + lane] = q;
    }
}

extern "C" void kernel_launch(void* const* d_in, const int* in_sizes, int n_in,
                              void* d_out, int out_size, void* d_ws, size_t ws_size,
                              hipStream_t stream)
{
    const float* h      = (const float*)d_in[0];
    const float* r      = (const float*)d_in[1];
    const int*   src    = (const int*)d_in[2];
    const int*   dst    = (const int*)d_in[3];
    const float* hn_a   = (const float*)d_in[4];
    const float* hn_b   = (const float*)d_in[5];
    const float* tn_a   = (const float*)d_in[6];
    const float* tn_b   = (const float*)d_in[7];
    const float* rn_a   = (const float*)d_in[8];
    const float* rn_b   = (const float*)d_in[9];
    const float* head_w = (const float*)d_in[10];
    const float* tail_w = (const float*)d_in[11];
    const float* rel_w  = (const float*)d_in[12];
    const float* fc_w   = (const float*)d_in[13];
    const float* fc_b   = (const float*)d_in[14];

    int N = in_sizes[0] / D_DIM;
    int E = in_sizes[2];

    // workspace layout (float units)
    float* base  = (float*)d_ws;
    float* eh    = base;                         // NA
    float* et    = base + NA;                    // NA
    int*   cnt   = (int*)(base + 2 * NA);        // NA
    int*   rankc = (int*)(base + 3 * NA);        // NA (contiguous with cnt: one memset)
    int*   offl  = (int*)(base + 4 * NA);        // NA
    int*   off   = (int*)(base + 5 * NA);        // NA (N+1 used)
    int*   bsum  = (int*)(base + 6 * NA);        // 256
    int*   bpre  = bsum + 256;                   // 256
    float* feat  = base + 6 * NA + 512;          // NA*128
    int2*  edata = (int2*)(feat + (size_t)NA * 128); // E

    hipMemsetAsync(cnt, 0, 2 * (size_t)NA * sizeof(int), stream);

    int B1 = (N + 256) >> 8;   // chunks covering indices 0..N inclusive

    k_node<<<(N * 16 + 255) / 256, 256, 0, stream>>>(
        h, hn_a, hn_b, tn_a, tn_b, head_w, tail_w, eh, et, N);
    k_histo<<<(E + 255) / 256, 256, 0, stream>>>(dst, cnt, E);
    k_scanA<<<B1, 256, 0, stream>>>(cnt, offl, bsum, N);
    k_scanB<<<1, 256, 0, stream>>>(bsum, bpre, B1);
    k_combine<<<(N + 1 + 255) / 256, 256, 0, stream>>>(offl, bpre, off, N);
    k_edge<<<(E * 16 + 255) / 256, 256, 0, stream>>>(
        r, rn_a, rn_b, rel_w, src, dst, eh, et, off, rankc, edata, E);
    k_gather<<<(N + 3) / 4, 256, 0, stream>>>(h, off, edata, feat, N);
    k_gemv<<<(N + 15) / 16, 256, 0, stream>>>(feat, fc_w, fc_b, (float*)d_out, N);
}

// Round 5
// 576.478 us; speedup vs baseline: 1.8425x; 1.0245x over previous
//
#include <hip/hip_runtime.h>
#include <stdint.h>

#define D_DIM 128
#define EPS_LN 1e-6f
#define NA 20480   // padded node-array stride (N=20000 fits, N+1 ok)

// robust fast tanh: exact at +/-inf, ~1e-6 rel err
__device__ __forceinline__ float tanh_fast(float x) {
    return 1.0f - 2.0f / (__expf(2.0f * x) + 1.0f);
}

__device__ __forceinline__ float wave_sum(float v) {
    #pragma unroll
    for (int m = 1; m < 64; m <<= 1) v += __shfl_xor(v, m, 64);
    return v;
}

// reduce across a 16-lane group (xor masks 1,2,4,8 stay inside the group)
__device__ __forceinline__ float group16_sum(float v) {
    #pragma unroll
    for (int m = 1; m < 16; m <<= 1) v += __shfl_xor(v, m, 64);
    return v;
}

__device__ __forceinline__ float dot8_ln(const float4& a, const float4& b,
                                         float mean, float inv,
                                         const float4& wa0, const float4& wa1,
                                         const float4& wb0, const float4& wb1,
                                         const float4& ww0, const float4& ww1) {
    float p = 0.0f;
    p += ((a.x - mean) * inv * wa0.x + wb0.x) * ww0.x;
    p += ((a.y - mean) * inv * wa0.y + wb0.y) * ww0.y;
    p += ((a.z - mean) * inv * wa0.z + wb0.z) * ww0.z;
    p += ((a.w - mean) * inv * wa0.w + wb0.w) * ww0.w;
    p += ((b.x - mean) * inv * wa1.x + wb1.x) * ww1.x;
    p += ((b.y - mean) * inv * wa1.y + wb1.y) * ww1.y;
    p += ((b.z - mean) * inv * wa1.z + wb1.z) * ww1.z;
    p += ((b.w - mean) * inv * wa1.w + wb1.w) * ww1.w;
    return p;
}

// ---------------- per-node logits + fused degree histogram
// 16 lanes per node for eh/et; then grid-stride edge loop builds cnt histogram
// (overlaps scattered atomics with LN compute of other waves; saves a dispatch).
__global__ __launch_bounds__(256) void k_node(
    const float* __restrict__ h,
    const float* __restrict__ hn_a, const float* __restrict__ hn_b,
    const float* __restrict__ tn_a, const float* __restrict__ tn_b,
    const float* __restrict__ head_w, const float* __restrict__ tail_w,
    const int* __restrict__ dst, int* __restrict__ cnt,
    float* __restrict__ eh, float* __restrict__ et, int n, int nE)
{
    int gid  = blockIdx.x * 256 + threadIdx.x;
    int node = gid >> 4;
    int sub  = threadIdx.x & 15;

    if (node < n) {
        const float4* hp = (const float4*)(h + (size_t)node * 128);
        float4 a = hp[sub * 2], b = hp[sub * 2 + 1];

        float s  = a.x + a.y + a.z + a.w + b.x + b.y + b.z + b.w;
        float s2 = a.x*a.x + a.y*a.y + a.z*a.z + a.w*a.w
                 + b.x*b.x + b.y*b.y + b.z*b.z + b.w*b.w;
        s  = group16_sum(s);
        s2 = group16_sum(s2);
        float mean = s * (1.0f / 128.0f);
        float var  = fmaxf((s2 - s * mean) * (1.0f / 127.0f), 0.0f);
        float inv  = 1.0f / (sqrtf(var) + EPS_LN);

        int i0 = sub * 2, i1 = sub * 2 + 1;
        float4 ha0 = ((const float4*)hn_a)[i0],  ha1 = ((const float4*)hn_a)[i1];
        float4 hb0 = ((const float4*)hn_b)[i0],  hb1 = ((const float4*)hn_b)[i1];
        float4 hw0 = ((const float4*)head_w)[i0],hw1 = ((const float4*)head_w)[i1];
        float4 ta0 = ((const float4*)tn_a)[i0],  ta1 = ((const float4*)tn_a)[i1];
        float4 tb0 = ((const float4*)tn_b)[i0],  tb1 = ((const float4*)tn_b)[i1];
        float4 tw0 = ((const float4*)tail_w)[i0],tw1 = ((const float4*)tail_w)[i1];

        float ph = dot8_ln(a, b, mean, inv, ha0, ha1, hb0, hb1, hw0, hw1);
        float pt = dot8_ln(a, b, mean, inv, ta0, ta1, tb0, tb1, tw0, tw1);
        ph = group16_sum(ph);
        pt = group16_sum(pt);

        if (sub == 0) {
            eh[node] = tanh_fast(ph);
            et[node] = tanh_fast(pt);
        }
    }

    // fused histogram (memset of cnt precedes this kernel on the stream)
    int gthreads = gridDim.x * 256;
    for (int e = gid; e < nE; e += gthreads)
        atomicAdd(cnt + dst[e], 1);
}

// ---------------- parallel scan stage A: per-chunk (256-wide) exclusive scan + chunk totals
__global__ __launch_bounds__(256) void k_scanA(
    const int* __restrict__ cnt, int* __restrict__ offl,
    int* __restrict__ bsum, int n)
{
    __shared__ int sscan[4];
    int b = blockIdx.x;
    int i = (b << 8) + threadIdx.x;
    int v = (i < n) ? cnt[i] : 0;
    int lane = threadIdx.x & 63, w4 = threadIdx.x >> 6;
    int x = v;
    #pragma unroll
    for (int s = 1; s < 64; s <<= 1) {
        int t = __shfl_up(x, s, 64);
        if (lane >= s) x += t;
    }
    if (lane == 63) sscan[w4] = x;
    __syncthreads();
    if (threadIdx.x == 0) {
        int a0 = sscan[0], a1 = sscan[1], a2 = sscan[2], a3 = sscan[3];
        sscan[0] = 0; sscan[1] = a0; sscan[2] = a0 + a1; sscan[3] = a0 + a1 + a2;
        bsum[b] = a0 + a1 + a2 + a3;
    }
    __syncthreads();
    offl[i] = sscan[w4] + x - v;   // chunk-local exclusive
}

// ---------------- scan stage B: exclusive scan of chunk totals (1 block, nb<=256)
__global__ __launch_bounds__(256) void k_scanB(
    const int* __restrict__ bsum, int* __restrict__ bpre, int nb)
{
    __shared__ int sscan[4];
    int t = threadIdx.x;
    int v = (t < nb) ? bsum[t] : 0;
    int lane = t & 63, w4 = t >> 6;
    int x = v;
    #pragma unroll
    for (int s = 1; s < 64; s <<= 1) {
        int tt = __shfl_up(x, s, 64);
        if (lane >= s) x += tt;
    }
    if (lane == 63) sscan[w4] = x;
    __syncthreads();
    if (t == 0) {
        int a0 = sscan[0], a1 = sscan[1], a2 = sscan[2], a3 = sscan[3];
        sscan[0] = 0; sscan[1] = a0; sscan[2] = a0 + a1; sscan[3] = a0 + a1 + a2;
    }
    __syncthreads();
    bpre[t] = sscan[w4] + x - v;
}

// ---------------- per-edge: er = tanh(LN(r;rn)·rel_w); e = relu(eh[src]+et[dst]+er)
// Writes CSR slot DIRECTLY: slot = off(dst) + rank, off computed on the fly
// from offl + bpre (bpre is 79 ints, L1-resident). One packed 8B store.
__global__ __launch_bounds__(256) void k_edge(
    const float* __restrict__ r,
    const float* __restrict__ rn_a, const float* __restrict__ rn_b,
    const float* __restrict__ rel_w,
    const int* __restrict__ src, const int* __restrict__ dst,
    const float* __restrict__ eh, const float* __restrict__ et,
    const int* __restrict__ offl, const int* __restrict__ bpre,
    int* __restrict__ rankc, int2* __restrict__ edata, int nE)
{
    int gid  = blockIdx.x * 256 + threadIdx.x;
    int edge = gid >> 4;
    int sub  = threadIdx.x & 15;
    if (edge >= nE) return;

    // early prefetch (writer lane only); latency overlaps LN compute below
    int sN = 0, dN = 0, base = 0;
    float vh = 0.0f, vt = 0.0f;
    if (sub == 0) {
        sN = src[edge]; dN = dst[edge];
        vh = eh[sN];    vt = et[dN];
        base = offl[dN] + bpre[dN >> 8];
    }

    const float4* rp = (const float4*)(r + (size_t)edge * 128);
    float4 a = rp[sub * 2], b = rp[sub * 2 + 1];

    float s  = a.x + a.y + a.z + a.w + b.x + b.y + b.z + b.w;
    float s2 = a.x*a.x + a.y*a.y + a.z*a.z + a.w*a.w
             + b.x*b.x + b.y*b.y + b.z*b.z + b.w*b.w;
    s  = group16_sum(s);
    s2 = group16_sum(s2);
    float mean = s * (1.0f / 128.0f);
    float var  = fmaxf((s2 - s * mean) * (1.0f / 127.0f), 0.0f);
    float inv  = 1.0f / (sqrtf(var) + EPS_LN);

    int i0 = sub * 2, i1 = sub * 2 + 1;
    float4 ra0 = ((const float4*)rn_a)[i0],  ra1 = ((const float4*)rn_a)[i1];
    float4 rb0 = ((const float4*)rn_b)[i0],  rb1 = ((const float4*)rn_b)[i1];
    float4 rw0 = ((const float4*)rel_w)[i0], rw1 = ((const float4*)rel_w)[i1];

    float pr = dot8_ln(a, b, mean, inv, ra0, ra1, rb0, rb1, rw0, rw1);
    pr = group16_sum(pr);

    if (sub == 0) {
        float v = tanh_fast(pr) + vh + vt;
        v = fmaxf(v, 0.0f);                 // e in [0,3): exp safe un-shifted
        int rank = atomicAdd(rankc + dN, 1);
        edata[base + rank] = make_int2(sN, __float_as_int(__expf(v)));
    }
}

// ---------------- per-node gather: feat[v] = (1/sum w) * sum w*h[src]
// One wave per node, TWO edges per wave-step: lanes 0-31 = edge 2p,
// lanes 32-63 = edge 2p+1, float4 (16B) per lane. 4 pairs (8 edges) in
// flight per chunk. Halves combined with shfl_xor(32) at the end.
__global__ __launch_bounds__(256) void k_gather(
    const float* __restrict__ h,
    const int* __restrict__ offl, const int* __restrict__ bpre,
    const int2* __restrict__ edata,
    float* __restrict__ feat, int n)
{
    int wid = threadIdx.x >> 6, lane = threadIdx.x & 63;
    int v = blockIdx.x * 4 + wid;
    if (v >= n) return;
    int half = lane >> 5, l5 = lane & 31;

    int beg = offl[v]     + bpre[v >> 8];
    int end = offl[v + 1] + bpre[(v + 1) >> 8];

    const float4* h4 = (const float4*)h;

    float a0 = 0.0f, a1 = 0.0f, a2 = 0.0f, a3 = 0.0f, ws = 0.0f;

    for (int i = beg; i < end; i += 8) {
        int2   q_[4];
        float4 p_[4];
        bool   ok_[4];
        #pragma unroll
        for (int pp = 0; pp < 4; pp++) {
            int e = i + 2 * pp + half;
            ok_[pp] = (e < end);
            if (ok_[pp]) q_[pp] = edata[e];
        }
        #pragma unroll
        for (int pp = 0; pp < 4; pp++)
            if (ok_[pp]) p_[pp] = h4[(size_t)q_[pp].x * 32 + l5];
        #pragma unroll
        for (int pp = 0; pp < 4; pp++)
            if (ok_[pp]) {
                float w = __int_as_float(q_[pp].y);
                a0 += w * p_[pp].x; a1 += w * p_[pp].y;
                a2 += w * p_[pp].z; a3 += w * p_[pp].w;
                ws += w;
            }
    }
    a0 += __shfl_xor(a0, 32, 64);
    a1 += __shfl_xor(a1, 32, 64);
    a2 += __shfl_xor(a2, 32, 64);
    a3 += __shfl_xor(a3, 32, 64);
    ws += __shfl_xor(ws, 32, 64);

    float inv = (end > beg) ? (1.0f / ws) : 0.0f;
    if (half == 0) {
        float4 qo;
        qo.x = a0 * inv; qo.y = a1 * inv; qo.z = a2 * inv; qo.w = a3 * inv;
        ((float4*)feat)[(size_t)v * 32 + l5] = qo;   // lanes 0-31: 512B contiguous
    }
}

// ---------------- GEMV + L2-normalize: out[v] = normalize(feat[v]@W + b)
// 16 nodes/block; fc_w staged in LDS in 32KB halves, shared by 4 waves
// (cuts fc_w L2 traffic 16x vs per-wave streaming). feat staged in LDS (8KB).
__global__ __launch_bounds__(256) void k_gemv(
    const float* __restrict__ feat,
    const float* __restrict__ fc_w, const float* __restrict__ fc_b,
    float* __restrict__ out, int n)
{
    __shared__ float wl[64][128];   // 32 KB: half of fc_w
    __shared__ float fl[16][128];   // 8 KB: this block's 16 feat rows
    int tid = threadIdx.x, lane = tid & 63, wid = tid >> 6;
    int vbase = blockIdx.x * 16;

    // stage feat rows (zero-pad past n)
    {
        const float4* fp = (const float4*)(feat + (size_t)vbase * 128);
        for (int k = tid; k < 512; k += 256) {       // 512 float4 = 16x128
            int row = k >> 5;
            ((float4*)fl)[k] = (vbase + row < n) ? fp[k] : make_float4(0, 0, 0, 0);
        }
    }

    float o0[4], o1[4];
    float2 bb = ((const float2*)fc_b)[lane];
    #pragma unroll
    for (int t = 0; t < 4; t++) { o0[t] = bb.x; o1[t] = bb.y; }

    for (int half = 0; half < 2; half++) {
        __syncthreads();   // feat staged (iter0) / previous compute done (iter1)
        const float4* wp = (const float4*)(fc_w + half * 64 * 128);
        for (int k = tid; k < 2048; k += 256)        // 2048 float4 = 64x128
            ((float4*)wl)[k] = wp[k];
        __syncthreads();
        #pragma unroll 4
        for (int d = 0; d < 64; d++) {
            float2 ww = ((const float2*)(wl[d]))[lane];   // contiguous, conflict-free
            #pragma unroll
            for (int t = 0; t < 4; t++) {
                float f = fl[wid * 4 + t][half * 64 + d]; // LDS broadcast
                o0[t] += f * ww.x;
                o1[t] += f * ww.y;
            }
        }
    }

    #pragma unroll
    for (int t = 0; t < 4; t++) {
        int v = vbase + wid * 4 + t;
        if (v >= n) continue;
        float nrm2 = wave_sum(o0[t] * o0[t] + o1[t] * o1[t]);
        float invn = 1.0f / fmaxf(sqrtf(nrm2), 1e-12f);
        float2 q; q.x = o0[t] * invn; q.y = o1[t] * invn;
        ((float2*)out)[(size_t)v * 64 + lane] = q;
    }
}

extern "C" void kernel_launch(void* const* d_in, const int* in_sizes, int n_in,
                              void* d_out, int out_size, void* d_ws, size_t ws_size,
                              hipStream_t stream)
{
    const float* h      = (const float*)d_in[0];
    const float* r      = (const float*)d_in[1];
    const int*   src    = (const int*)d_in[2];
    const int*   dst    = (const int*)d_in[3];
    const float* hn_a   = (const float*)d_in[4];
    const float* hn_b   = (const float*)d_in[5];
    const float* tn_a   = (const float*)d_in[6];
    const float* tn_b   = (const float*)d_in[7];
    const float* rn_a   = (const float*)d_in[8];
    const float* rn_b   = (const float*)d_in[9];
    const float* head_w = (const float*)d_in[10];
    const float* tail_w = (const float*)d_in[11];
    const float* rel_w  = (const float*)d_in[12];
    const float* fc_w   = (const float*)d_in[13];
    const float* fc_b   = (const float*)d_in[14];

    int N = in_sizes[0] / D_DIM;
    int E = in_sizes[2];

    // workspace layout (float units)
    float* base  = (float*)d_ws;
    float* eh    = base;                         // NA
    float* et    = base + NA;                    // NA
    int*   cnt   = (int*)(base + 2 * NA);        // NA
    int*   rankc = (int*)(base + 3 * NA);        // NA (contiguous with cnt: one memset)
    int*   offl  = (int*)(base + 4 * NA);        // NA
    int*   bsum  = (int*)(base + 5 * NA);        // 256
    int*   bpre  = bsum + 256;                   // 256
    float* feat  = base + 5 * NA + 512;          // NA*128
    int2*  edata = (int2*)(feat + (size_t)NA * 128); // E

    hipMemsetAsync(cnt, 0, 2 * (size_t)NA * sizeof(int), stream);

    int B1 = (N + 256) >> 8;   // chunks covering indices 0..N inclusive

    k_node<<<(N * 16 + 255) / 256, 256, 0, stream>>>(
        h, hn_a, hn_b, tn_a, tn_b, head_w, tail_w, dst, cnt, eh, et, N, E);
    k_scanA<<<B1, 256, 0, stream>>>(cnt, offl, bsum, N);
    k_scanB<<<1, 256, 0, stream>>>(bsum, bpre, B1);
    k_edge<<<(E * 16 + 255) / 256, 256, 0, stream>>>(
        r, rn_a, rn_b, rel_w, src, dst, eh, et, offl, bpre, rankc, edata, E);
    k_gather<<<(N + 3) / 4, 256, 0, stream>>>(h, offl, bpre, edata, feat, N);
    k_gemv<<<(N + 15) / 16, 256, 0, stream>>>(feat, fc_w, fc_b, (float*)d_out, N);
}